// Round 1
// baseline (10251.544 us; speedup 1.0000x reference)
//
#include <hip/hip_runtime.h>
#include <hip/hip_bf16.h>
#include <stdint.h>

typedef __bf16  bf16x8 __attribute__((ext_vector_type(8)));
typedef float   f32x16 __attribute__((ext_vector_type(16)));

#define NB   64
#define NT   1024
#define ND   256
#define NH   512
#define NWGD 32

// LDS layout (bytes)
#define LDS_WFR   0                        // 48*2*64*8 bf16 = 98304
#define LDS_RED   98304                    // 4*64*17 f32   = 17408
#define LDS_HOUT  (98304+17408)            // 64*16 bf16    = 2048
#define LDS_BIAS  (98304+17408+2048)       // 64 f32        = 256
#define LDS_TOTAL (98304+17408+2048+256)   // 118016 -> 1 WG/CU

static __device__ __forceinline__ unsigned long long agent_load_u64(const void* p) {
  return __hip_atomic_load((const unsigned long long*)p, __ATOMIC_RELAXED,
                           __HIP_MEMORY_SCOPE_AGENT);
}
static __device__ __forceinline__ void agent_store_u64(void* p, unsigned long long v) {
  __hip_atomic_store((unsigned long long*)p, v, __ATOMIC_RELAXED,
                     __HIP_MEMORY_SCOPE_AGENT);
}
static __device__ __forceinline__ float fast_sigmoid(float v) {
  return __builtin_amdgcn_rcpf(1.0f + __expf(-v));
}
static __device__ __forceinline__ float fast_tanh(float v) {
  // 1 - 2/(1+e^{2x}) : monotone, saturates correctly, no inf/inf NaN
  return 1.0f - 2.0f * __builtin_amdgcn_rcpf(1.0f + __expf(2.0f * v));
}

// Persistent bidirectional LSTM. Grid = 64 WGs: bid>>5 = direction, bid&31 = j
// (hidden-unit slice, 16 units => 64 gate columns, gate-interleaved n=4u+g).
// Gemm per step: G^T[64 cols][64 batch] = Wslice^T[64][768] @ act^T[768][64],
// mfma_f32_32x32x16_bf16, tiles (mi: col-tile 0..1) x (ni: batch-tile 0..1).
// Waves = (ni, kh): kh splits K in halves; stride-17 LDS reduction joins them.
__global__ __launch_bounds__(256, 1) void bilstm_persist(
    const float* __restrict__ x,
    const float* __restrict__ Wf, const float* __restrict__ bf_,
    const float* __restrict__ Wb, const float* __restrict__ bb_,
    __hip_bfloat16* __restrict__ hbuf, unsigned int* __restrict__ cnt)
{
  extern __shared__ char smem[];
  __bf16*         wfr   = (__bf16*)(smem + LDS_WFR);
  float*          red   = (float*) (smem + LDS_RED);
  __hip_bfloat16* hout  = (__hip_bfloat16*)(smem + LDS_HOUT);
  float*          biasl = (float*) (smem + LDS_BIAS);

  const int tid = threadIdx.x;
  const int bid = blockIdx.x;
  const int dir = bid >> 5;
  const int jsl = bid & 31;

  const float* W  = dir ? Wb  : Wf;
  const float* bi = dir ? bb_ : bf_;

  const int lane = tid & 63;
  const int wid  = tid >> 6;
  const int ni   = wid & 1;     // batch tile
  const int kh   = wid >> 1;    // K half
  const int hi   = lane >> 5;
  const int bcol = ni * 32 + (lane & 31);   // batch row this lane owns (B-operand col)

  // ---- bias slice -> LDS (local col n: gate = n&3, unit u = n>>2) ----
  if (tid < 64) {
    biasl[tid] = bi[(tid & 3) * 512 + jsl * 16 + (tid >> 2)];
  }
  // ---- W slice -> LDS in A-fragment order: wfr[((kk*2+mi)*64+lane)*8+v] ----
  // frag value = W[k][gcol], k = kk*16 + (lane>>5)*8 + v, n = mi*32+(lane&31),
  // gcol = (n&3)*512 + jsl*16 + (n>>2).  (same k-hat used on both operands)
  for (int i = tid; i < 48*2*64*8; i += 256) {
    const int ln = i & 63;
    const int r2 = i >> 6;
    const int v  = r2 & 7;
    const int m2 = (r2 >> 3) & 1;
    const int kk = r2 >> 4;
    const int k  = kk*16 + (ln >> 5)*8 + v;
    const int n  = m2*32 + (ln & 31);
    const int gcol = (n & 3)*512 + jsl*16 + (n >> 2);
    wfr[((size_t)(kk*2 + m2)*64 + ln)*8 + v] = (__bf16)W[(size_t)k*2048 + gcol];
  }
  __syncthreads();

  // bias in regs; only kh==0 waves carry it (they finalize after reduction)
  float biasr[2][16];
  #pragma unroll
  for (int mi = 0; mi < 2; ++mi)
    #pragma unroll
    for (int r = 0; r < 16; ++r)
      biasr[mi][r] = (kh == 0) ? biasl[mi*32 + (r & 3) + 8*(r >> 2) + 4*hi] : 0.0f;

  float creg[8];  // cell state, (mi,s) pairs, lives in registers for all T steps
  #pragma unroll
  for (int i = 0; i < 8; ++i) creg[i] = 0.0f;

  __hip_bfloat16* hb = hbuf + (size_t)dir * (2*NB*NH);   // [phase][64][512]
  unsigned int* mycnt = cnt + dir * NT;

  for (int t = 0; t < NT; ++t) {
    const int trow = dir ? (NT - 1 - t) : t;
    const __hip_bfloat16* hprev = hb + (size_t)(t & 1) * (NB*NH);
    __hip_bfloat16*       hnext = hb + (size_t)((t + 1) & 1) * (NB*NH);

    f32x16 acc0, acc1;
    #pragma unroll
    for (int r = 0; r < 16; ++r) { acc0[r] = biasr[0][r]; acc1[r] = biasr[1][r]; }

    const int kk0 = kh * 24;
    const float* xbase = x + ((size_t)bcol * NT + trow) * ND;
    const char*  hrow  = (const char*)(hprev + (size_t)bcol * NH);

    #pragma unroll 4
    for (int i = 0; i < 24; ++i) {
      const int kk = kk0 + i;
      const int k  = kk*16 + hi*8;
      bf16x8 bfr;
      if (k < ND) {                       // x part of [x_t | h]
        const float4 xa = *(const float4*)(xbase + k);
        const float4 xb = *(const float4*)(xbase + k + 4);
        bfr[0]=(__bf16)xa.x; bfr[1]=(__bf16)xa.y; bfr[2]=(__bf16)xa.z; bfr[3]=(__bf16)xa.w;
        bfr[4]=(__bf16)xb.x; bfr[5]=(__bf16)xb.y; bfr[6]=(__bf16)xb.z; bfr[7]=(__bf16)xb.w;
      } else {                            // h part: agent-scope coherent loads
        union { unsigned long long q[2]; bf16x8 v; } u;
        const int off = (k - ND) * 2;
        u.q[0] = agent_load_u64(hrow + off);
        u.q[1] = agent_load_u64(hrow + off + 8);
        bfr = u.v;
      }
      const bf16x8 a0 = *(const bf16x8*)(wfr + ((size_t)(kk*2 + 0)*64 + lane)*8);
      const bf16x8 a1 = *(const bf16x8*)(wfr + ((size_t)(kk*2 + 1)*64 + lane)*8);
      acc0 = __builtin_amdgcn_mfma_f32_32x32x16_bf16(a0, bfr, acc0, 0, 0, 0);
      acc1 = __builtin_amdgcn_mfma_f32_32x32x16_bf16(a1, bfr, acc1, 0, 0, 0);
    }

    // ---- cross-wave K reduction (stride 17 floats: conflict-free b32) ----
    if (kh == 1) {
      #pragma unroll
      for (int r = 0; r < 16; ++r) {
        red[((ni*2 + 0)*64 + lane)*17 + r] = acc0[r];
        red[((ni*2 + 1)*64 + lane)*17 + r] = acc1[r];
      }
    }
    __syncthreads();
    if (kh == 0) {
      #pragma unroll
      for (int r = 0; r < 16; ++r) {
        acc0[r] += red[((ni*2 + 0)*64 + lane)*17 + r];
        acc1[r] += red[((ni*2 + 1)*64 + lane)*17 + r];
      }
      // ---- elementwise: regs 4s..4s+3 of tile mi are f,i,o,g of one (u,b) ----
      #pragma unroll
      for (int mi = 0; mi < 2; ++mi) {
        const f32x16 aa = mi ? acc1 : acc0;
        #pragma unroll
        for (int s = 0; s < 4; ++s) {
          const float fg = fast_sigmoid(aa[4*s+0]);
          const float ig = fast_sigmoid(aa[4*s+1]);
          const float og = fast_sigmoid(aa[4*s+2]);
          const float gg = fast_tanh   (aa[4*s+3]);
          const int   p  = mi*4 + s;
          const float cn = fg * creg[p] + ig * gg;
          creg[p] = cn;
          const float hv = og * fast_tanh(cn);
          hout[bcol*16 + (mi*8 + 2*s + hi)] = __float2bfloat16(hv);
        }
      }
    }
    __syncthreads();
    // ---- coalesced agent-scope publish of this WG's h slice (2 KB) ----
    {
      const unsigned long long vv = ((const unsigned long long*)hout)[tid];
      const int b  = tid >> 2;
      const int u0 = (tid & 3) * 4;
      agent_store_u64(hnext + (size_t)b*NH + jsl*16 + u0, vv);
    }
    __syncthreads();   // drains vmcnt per wave before the barrier
    // ---- one counter-barrier per step across the direction's 32 WGs ----
    if (tid == 0) {
      __hip_atomic_fetch_add(&mycnt[t], 1u, __ATOMIC_RELAXED, __HIP_MEMORY_SCOPE_AGENT);
      while (__hip_atomic_load(&mycnt[t], __ATOMIC_RELAXED, __HIP_MEMORY_SCOPE_AGENT) < NWGD) {
        __builtin_amdgcn_s_sleep(1);
      }
    }
    __syncthreads();
  }
}

// out[b][o] = [h_fwd | h_bwd] @ W_fc + b_fc   (final h lives in phase 0)
__global__ __launch_bounds__(128) void fc_out(
    const __hip_bfloat16* __restrict__ hbuf, const float* __restrict__ Wfc,
    const float* __restrict__ bfc, float* __restrict__ out)
{
  __shared__ float hrow[2*NH];
  const int b = blockIdx.x, o = threadIdx.x;
  const __hip_bfloat16* hf  = hbuf + (size_t)b*NH;                    // dir0 phase0
  const __hip_bfloat16* hb2 = hbuf + (size_t)2*NB*NH + (size_t)b*NH;  // dir1 phase0
  for (int i = o; i < NH; i += 128) {
    hrow[i]      = __bfloat162float(hf[i]);
    hrow[NH + i] = __bfloat162float(hb2[i]);
  }
  __syncthreads();
  float acc = bfc[o];
  for (int k = 0; k < 2*NH; ++k)
    acc = fmaf(hrow[k], Wfc[(size_t)k*128 + o], acc);
  out[b*128 + o] = acc;
}

extern "C" void kernel_launch(void* const* d_in, const int* in_sizes, int n_in,
                              void* d_out, int out_size, void* d_ws, size_t ws_size,
                              hipStream_t stream) {
  (void)in_sizes; (void)n_in; (void)out_size; (void)ws_size;
  const float* x   = (const float*)d_in[0];
  const float* Wf  = (const float*)d_in[1];
  const float* bf_ = (const float*)d_in[2];
  const float* Wb  = (const float*)d_in[3];
  const float* bb_ = (const float*)d_in[4];
  const float* Wfc = (const float*)d_in[5];
  const float* bfc = (const float*)d_in[6];
  float* out = (float*)d_out;

  // ws: hbuf [2 dir][2 phase][64][512] bf16 = 262144 B, then cnt [2][1024] u32 = 8192 B
  __hip_bfloat16* hbuf = (__hip_bfloat16*)d_ws;
  unsigned int*   cnt  = (unsigned int*)((char*)d_ws + 2*2*NB*NH*2);

  hipMemsetAsync(d_ws, 0, 2*2*NB*NH*2 + 2*NT*4, stream);  // h0=c0=0, counters=0

  hipFuncSetAttribute((const void*)bilstm_persist,
                      hipFuncAttributeMaxDynamicSharedMemorySize, LDS_TOTAL);

  bilstm_persist<<<dim3(64), dim3(256), LDS_TOTAL, stream>>>(x, Wf, bf_, Wb, bb_, hbuf, cnt);
  fc_out<<<dim3(NB), dim3(128), 0, stream>>>(hbuf, Wfc, bfc, out);
}